// Round 2
// baseline (188.597 us; speedup 1.0000x reference)
//
#include <hip/hip_runtime.h>
#include <hip/hip_bf16.h>

// IcosahedronConv2d: out[b,v,o] = sum_{k,c} x[b, idx[v,k], c] * mask[v,k] * w[o,c,k] + bias[o]
// B=8, V=10242, C_IN=C_OUT=128, 9 k-slots. Gather-GEMM, bf16 MFMA.

#define V_CNT   10242
#define CC_IN   128
#define CC_OUT  128
#define KSLOTS  9
#define BM      128
#define VT_PER_B 81          // ceil(10242/128)
#define BATCH   8

typedef short short8 __attribute__((ext_vector_type(8)));
typedef float f32x4  __attribute__((ext_vector_type(4)));

__device__ __forceinline__ unsigned short f2bf(float f) {
    unsigned int u = __float_as_uint(f);
    u += 0x7fffu + ((u >> 16) & 1u);      // round-to-nearest-even
    return (unsigned short)(u >> 16);
}

// Prepass: w[o][c][k] f32  ->  Wb[k][o][c] bf16 (so per-k-step B staging is contiguous)
__global__ void wprep_kernel(const float* __restrict__ w, unsigned short* __restrict__ wb) {
    int i = blockIdx.x * 256 + threadIdx.x;
    if (i >= CC_OUT * CC_IN * KSLOTS) return;
    int o = i / (CC_IN * KSLOTS);
    int r = i - o * (CC_IN * KSLOTS);
    int c = r / KSLOTS;
    int k = r - c * KSLOTS;
    wb[((size_t)k * CC_OUT + o) * CC_IN + c] = f2bf(w[i]);
}

__global__ __launch_bounds__(256, 2)
void icoconv_kernel(const float* __restrict__ x, const unsigned short* __restrict__ wb,
                    const float* __restrict__ bias, const int* __restrict__ nidx,
                    const float* __restrict__ nmask, float* __restrict__ out) {
    // LDS: A tile [128 rows][128 bf16], B tile (W^T) [128 o-rows][128 bf16], both XOR-swizzled
    __shared__ __align__(16) unsigned short As[BM * 128];
    __shared__ __align__(16) unsigned short Bs[CC_OUT * 128];

    const int tid  = threadIdx.x;
    const int lane = tid & 63;
    const int wid  = tid >> 6;
    const int blk  = blockIdx.x;
    const int bb   = blk / VT_PER_B;
    const int vt   = blk - bb * VT_PER_B;
    const int vbase = vt * BM;

    // staging role: 2 threads per row, each does 64 columns
    const int sr = tid >> 1;
    const int sh = tid & 1;
    const int v  = vbase + sr;
    const bool valid = v < V_CNT;

    const int wave_m = wid >> 1;   // 0..1
    const int wave_n = wid & 1;    // 0..1

    f32x4 acc[4][4];
    #pragma unroll
    for (int i = 0; i < 4; ++i)
        #pragma unroll
        for (int j = 0; j < 4; ++j)
            acc[i][j] = f32x4{0.f, 0.f, 0.f, 0.f};

    const size_t xbatch = (size_t)bb * V_CNT * CC_IN;

    for (int ks = 0; ks < KSLOTS; ++ks) {
        int g = 0; float mk = 0.f;
        if (valid) {
            g  = nidx[v * KSLOTS + ks];
            mk = nmask[v * KSLOTS + ks];
        }
        // barrier (protects LDS from previous iteration's reads) + whole-tile mask check
        int any = __syncthreads_or(mk != 0.f);
        if (!any) continue;   // fully-masked k-slot: contributes zero

        // ---- stage A: gather x row, *mask, f32->bf16, swizzled LDS write ----
        {
            char* arow = (char*)As + sr * 256;
            if (valid && mk != 0.f) {
                const float4* src = (const float4*)(x + xbatch + (size_t)g * CC_IN + sh * 64);
                #pragma unroll
                for (int q = 0; q < 8; ++q) {
                    float4 f0 = src[2 * q];
                    float4 f1 = src[2 * q + 1];
                    uint4 pk;
                    pk.x = (unsigned)f2bf(f0.x * mk) | ((unsigned)f2bf(f0.y * mk) << 16);
                    pk.y = (unsigned)f2bf(f0.z * mk) | ((unsigned)f2bf(f0.w * mk) << 16);
                    pk.z = (unsigned)f2bf(f1.x * mk) | ((unsigned)f2bf(f1.y * mk) << 16);
                    pk.w = (unsigned)f2bf(f1.z * mk) | ((unsigned)f2bf(f1.w * mk) << 16);
                    int boff = (sh * 128 + q * 16) ^ ((sr & 7) << 4);
                    *(uint4*)(arow + boff) = pk;
                }
            } else {
                uint4 z = {0u, 0u, 0u, 0u};
                #pragma unroll
                for (int q = 0; q < 8; ++q) {
                    int boff = (sh * 128 + q * 16) ^ ((sr & 7) << 4);
                    *(uint4*)(arow + boff) = z;
                }
            }
        }
        // ---- stage B: contiguous bf16 copy of Wb[ks], swizzled ----
        {
            const uint4* src = (const uint4*)(wb + ((size_t)ks * CC_OUT + sr) * CC_IN + sh * 64);
            char* brow = (char*)Bs + sr * 256;
            #pragma unroll
            for (int q = 0; q < 8; ++q) {
                int boff = (sh * 128 + q * 16) ^ ((sr & 7) << 4);
                *(uint4*)(brow + boff) = src[q];
            }
        }
        __syncthreads();

        // ---- compute: 4 kk-steps of K=32, 16 MFMAs each per wave ----
        #pragma unroll
        for (int kk = 0; kk < 4; ++kk) {
            const int kb = kk * 64 + ((lane >> 4) << 4);   // byte offset of this lane-group's 8 bf16
            short8 af[4], bfr[4];
            #pragma unroll
            for (int mi = 0; mi < 4; ++mi) {
                int row = wave_m * 64 + mi * 16 + (lane & 15);
                af[mi] = *(const short8*)((const char*)As + row * 256 + (kb ^ ((row & 7) << 4)));
            }
            #pragma unroll
            for (int ni = 0; ni < 4; ++ni) {
                int col = wave_n * 64 + ni * 16 + (lane & 15);
                bfr[ni] = *(const short8*)((const char*)Bs + col * 256 + (kb ^ ((col & 7) << 4)));
            }
            #pragma unroll
            for (int mi = 0; mi < 4; ++mi)
                #pragma unroll
                for (int ni = 0; ni < 4; ++ni)
                    acc[mi][ni] = __builtin_amdgcn_mfma_f32_16x16x32_bf16(af[mi], bfr[ni], acc[mi][ni], 0, 0, 0);
        }
    }

    // ---- epilogue: D row=(lane>>4)*4+j, col=lane&15 (m89-verified layout) ----
    #pragma unroll
    for (int ni = 0; ni < 4; ++ni) {
        int col = wave_n * 64 + ni * 16 + (lane & 15);
        float bv = bias[col];
        #pragma unroll
        for (int mi = 0; mi < 4; ++mi) {
            #pragma unroll
            for (int j = 0; j < 4; ++j) {
                int row = wave_m * 64 + mi * 16 + ((lane >> 4) << 2) + j;
                int vv = vbase + row;
                if (vv < V_CNT)
                    out[((size_t)bb * V_CNT + vv) * CC_OUT + col] = acc[mi][ni][j] + bv;
            }
        }
    }
}

extern "C" void kernel_launch(void* const* d_in, const int* in_sizes, int n_in,
                              void* d_out, int out_size, void* d_ws, size_t ws_size,
                              hipStream_t stream) {
    const float* x     = (const float*)d_in[0];
    const float* w     = (const float*)d_in[1];
    const float* bias  = (const float*)d_in[2];
    const int*   nidx  = (const int*)d_in[3];
    const float* nmask = (const float*)d_in[4];
    float* out = (float*)d_out;

    unsigned short* wb = (unsigned short*)d_ws;   // 9*128*128 bf16 = 294912 B

    int wtot = CC_OUT * CC_IN * KSLOTS;
    wprep_kernel<<<(wtot + 255) / 256, 256, 0, stream>>>(w, wb);

    int nblk = BATCH * VT_PER_B;   // 648
    icoconv_kernel<<<nblk, 256, 0, stream>>>(x, wb, bias, nidx, nmask, out);
}